// Round 4
// baseline (294.075 us; speedup 1.0000x reference)
//
#include <hip/hip_runtime.h>
#include <math.h>

static constexpr float kL1   = 0.5f;
static constexpr float kL2   = 1.5f;
static constexpr float kBeta = 50000000.0f;
static constexpr float kEps  = 1e-08f;

__device__ __forceinline__ float waveSum(float v) {
#pragma unroll
    for (int off = 32; off > 0; off >>= 1) v += __shfl_xor(v, off, 64);
    return v;
}

__device__ __forceinline__ float tubeTail(float dot, float pp, float gg) {
    float p_norm = sqrtf(pp);
    float g_norm = sqrtf(gg);
    float denom  = p_norm * g_norm;
    float cosine = (denom == 0.0f) ? 0.0f : dot / denom;
    float s_s    = 1.0f - cosine * cosine;
    float sine   = (s_s < 0.0f) ? 0.0f : sqrtf((s_s <= 0.0f) ? kEps : s_s);
    float gd     = (g_norm == 0.0f) ? (g_norm + kEps) : g_norm;
    float pc     = p_norm * cosine;
    float r_all  = pc / gd;
    float base   = p_norm * sine + fabsf(g_norm - pc);
    float ds     = (r_all >= 1.0f) ? (kL1 * base)
                 : ((r_all >= 0.0f) ? base
                                    : kL2 * fabsf(pc - g_norm - p_norm * sine));
    // -log(tanh(t)) = log(1+e^{-2t}) - log(1-e^{-2t})
    float t  = 1.0f / ds;
    float em = __expf(-2.0f * t);
    return __logf(1.0f + em) - __logf(fmaxf(1.0f - em, 1e-30f));
}

// ---- TUBE: 4 lanes per row, 16 rows per wave, 32-deep k-loop ----
// grid: 1024 blocks x 256 -> 4096 waves -> 65536 rows, one row-group/wave
__global__ __launch_bounds__(256) void tube_kernel(
    const float* __restrict__ comple_out, const float* __restrict__ labels_enc,
    const float* __restrict__ xA,  const float* __restrict__ xAr,
    const float* __restrict__ xB,  const float* __restrict__ xBr,
    const float* __restrict__ xC,  const float* __restrict__ xCr,
    float* __restrict__ partials)
{
    const int lane = threadIdx.x & 63;
    const int wave = threadIdx.x >> 6;
    const int sub  = lane & 3;         // lane within 4-lane row group
    const int grp  = lane >> 2;        // row group 0..15 within wave
    const int B = 16384, D = 512;

    const int gw      = blockIdx.x * 4 + wave;   // 0..4095
    const int rowBase = gw * 16;                 // wave-uniform, pair-aligned
    const int pair    = rowBase >> 14;           // /16384
    const int r0      = rowBase & (B - 1);

    const float* att; const float* lab;
    if      (pair == 0) { att = xAr;        lab = xA;         }
    else if (pair == 1) { att = xBr;        lab = xB;         }
    else if (pair == 2) { att = xCr;        lab = xC;         }
    else                { att = comple_out; lab = labels_enc; }

    const float4* a4 = (const float4*)(att + (size_t)(r0 + grp) * D);
    const float4* l4 = (const float4*)(lab + (size_t)(r0 + grp) * D);

    float dot = 0.f, pp = 0.f, gg = 0.f;
#pragma unroll 4
    for (int k = 0; k < 32; ++k) {
        float4 a = a4[sub + 4 * k];    // 4 lanes -> 64B contiguous per row
        float4 l = l4[sub + 4 * k];
        dot += a.x * l.x + a.y * l.y + a.z * l.z + a.w * l.w;
        pp  += a.x * a.x + a.y * a.y + a.z * a.z + a.w * a.w;
        gg  += l.x * l.x + l.y * l.y + l.z * l.z + l.w * l.w;
    }
    // 2-step butterfly within each 4-lane group (covers all 16 rows at once)
#pragma unroll
    for (int off = 1; off <= 2; off <<= 1) {
        dot += __shfl_xor(dot, off, 64);
        pp  += __shfl_xor(pp,  off, 64);
        gg  += __shfl_xor(gg,  off, 64);
    }
    float my = 0.0f;
    if (sub == 0) my = tubeTail(dot, pp, gg) / (float)B;  // 16 lanes active

    float s = waveSum(my);
    __shared__ float sw[4];
    if (lane == 0) sw[wave] = s;
    __syncthreads();
    if (threadIdx.x == 0)
        partials[blockIdx.x] = sw[0] + sw[1] + sw[2] + sw[3];
}

// ---- KL: grid-stride float4 ----
__global__ __launch_bounds__(256) void kl_kernel(
    const float* __restrict__ mu, const float* __restrict__ logvar,
    float* __restrict__ partials, int n4)
{
    const int tid    = blockIdx.x * blockDim.x + threadIdx.x;
    const int stride = gridDim.x * blockDim.x;
    const float4* mu4 = (const float4*)mu;
    const float4* lv4 = (const float4*)logvar;
    float acc = 0.0f;
    for (int i = tid; i < n4; i += stride) {
        float4 m = mu4[i];
        float4 l = lv4[i];
        acc += (1.0f + l.x - m.x * m.x - __expf(l.x));
        acc += (1.0f + l.y - m.y * m.y - __expf(l.y));
        acc += (1.0f + l.z - m.z * m.z - __expf(l.z));
        acc += (1.0f + l.w - m.w * m.w - __expf(l.w));
    }
    float my = acc * (-0.5f * kBeta / (float)(16384 * 128));
    float s = waveSum(my);
    __shared__ float sw[4];
    const int lane = threadIdx.x & 63, wave = threadIdx.x >> 6;
    if (lane == 0) sw[wave] = s;
    __syncthreads();
    if (threadIdx.x == 0)
        partials[blockIdx.x] = sw[0] + sw[1] + sw[2] + sw[3];
}

// ---- CE: one wave per row over C=100 ----
__global__ __launch_bounds__(256) void ce_kernel(
    const float* __restrict__ fusion_out, const float* __restrict__ labels,
    float* __restrict__ partials, int B, int C)
{
    const int lane = threadIdx.x & 63;
    const int wave = threadIdx.x >> 6;
    const int globalWave = blockIdx.x * 4 + wave;
    const int totalWaves = gridDim.x * 4;
    float acc = 0.0f;
    for (int r = globalWave; r < B; r += totalWaves) {
        const float* lrow = labels     + (size_t)r * C;
        const float* frow = fusion_out + (size_t)r * C;
        const bool has0 = (lane < C);
        const bool has1 = (lane + 64 < C);
        float v0 = has0 ? lrow[lane]      : -INFINITY;
        float v1 = has1 ? lrow[lane + 64] : -INFINITY;
        float f0 = has0 ? frow[lane]      : -INFINITY;
        float f1 = has1 ? frow[lane + 64] : -INFINITY;
        float bv; int bi;
        if (v1 > v0) { bv = v1; bi = lane + 64; } else { bv = v0; bi = lane; }
#pragma unroll
        for (int off = 32; off > 0; off >>= 1) {
            float ov = __shfl_xor(bv, off, 64);
            int   oi = __shfl_xor(bi, off, 64);
            if (ov > bv || (ov == bv && oi < bi)) { bv = ov; bi = oi; }
        }
        float m = fmaxf(f0, f1);
#pragma unroll
        for (int off = 32; off > 0; off >>= 1) m = fmaxf(m, __shfl_xor(m, off, 64));
        float e = 0.0f;
        if (has0) e += __expf(f0 - m);
        if (has1) e += __expf(f1 - m);
        e = waveSum(e);
        float t = (bi < 64) ? __shfl(f0, bi, 64) : __shfl(f1, bi - 64, 64);
        if (lane == 0) acc += -(t - m - __logf(e));
    }
    float my = acc / (float)B;
    float s = waveSum(my);
    __shared__ float sw[4];
    if (lane == 0) sw[wave] = s;
    __syncthreads();
    if (threadIdx.x == 0)
        partials[blockIdx.x] = sw[0] + sw[1] + sw[2] + sw[3];
}

__global__ __launch_bounds__(256) void reduce_partials(
    const float* __restrict__ partials, float* __restrict__ out, int n)
{
    float s = 0.0f;
    for (int i = threadIdx.x; i < n; i += 256) s += partials[i];
    s = waveSum(s);
    __shared__ float sw[4];
    const int lane = threadIdx.x & 63;
    const int wave = threadIdx.x >> 6;
    if (lane == 0) sw[wave] = s;
    __syncthreads();
    if (threadIdx.x == 0) out[0] = sw[0] + sw[1] + sw[2] + sw[3];
}

extern "C" void kernel_launch(void* const* d_in, const int* in_sizes, int n_in,
                              void* d_out, int out_size, void* d_ws, size_t ws_size,
                              hipStream_t stream) {
    const float* fusion_out = (const float*)d_in[0];
    const float* comple_out = (const float*)d_in[1];
    const float* labels     = (const float*)d_in[2];
    const float* labels_enc = (const float*)d_in[3];
    const float* xA  = (const float*)d_in[4];
    const float* xAr = (const float*)d_in[5];
    const float* xB  = (const float*)d_in[6];
    const float* xBr = (const float*)d_in[7];
    const float* xC  = (const float*)d_in[8];
    const float* xCr = (const float*)d_in[9];
    const float* mu  = (const float*)d_in[10];
    const float* lv  = (const float*)d_in[11];
    float* out = (float*)d_out;
    float* ws  = (float*)d_ws;

    const int B = 16384;
    const int C = in_sizes[0] / B;    // 100
    const int Z = in_sizes[10] / B;   // 128

    const int tubeBlocks = 1024;      // 4096 waves x 16 rows = 65536 rows
    const int klBlocks   = 256;
    const int ceBlocks   = 2048;
    const int totalP = tubeBlocks + klBlocks + ceBlocks;

    float* pTube = ws;
    float* pKl   = ws + tubeBlocks;
    float* pCe   = ws + tubeBlocks + klBlocks;

    tube_kernel<<<tubeBlocks, 256, 0, stream>>>(
        comple_out, labels_enc, xA, xAr, xB, xBr, xC, xCr, pTube);
    kl_kernel<<<klBlocks, 256, 0, stream>>>(mu, lv, pKl, (B * Z) / 4);
    ce_kernel<<<ceBlocks, 256, 0, stream>>>(fusion_out, labels, pCe, B, C);
    reduce_partials<<<1, 256, 0, stream>>>(ws, out, totalP);
}